// Round 8
// baseline (233.360 us; speedup 1.0000x reference)
//
#include <hip/hip_runtime.h>
#include <hip/hip_fp16.h>

#define Nn 256
#define DKk 128

typedef unsigned short u16;
typedef __attribute__((ext_vector_type(8))) short bfrag;   // 8 bf16 = 4 VGPR
typedef __attribute__((ext_vector_type(4))) float f4;

#define MFMA16(a, b, c) __builtin_amdgcn_mfma_f32_16x16x32_bf16((a), (b), (c), 0, 0, 0)

__device__ __forceinline__ u16 f2b(float f) {
  unsigned int u = __builtin_bit_cast(unsigned int, f);
  u += 0x7fffu + ((u >> 16) & 1u);      // RNE
  return (u16)(u >> 16);
}

typedef __attribute__((address_space(1))) void GV;
typedef __attribute__((address_space(3))) void LV;
__device__ __forceinline__ void gload16(const void* g, void* l) {
  __builtin_amdgcn_global_load_lds((GV*)g, (LV*)l, 16, 0, 0);
}

// ------------------------------------- fused: cast x | transpose W | geo prior
// grid 12288: [0,4096) cast x->bf16; [4096,8192) W transpose+cast; [8192,12288) geo
__global__ __launch_bounds__(256) void pre_kernel(
    const float* __restrict__ x, const float* __restrict__ boxes,
    const float* __restrict__ Wq, const float* __restrict__ Wk,
    const float* __restrict__ Wv, const float* __restrict__ Wo,
    const float* __restrict__ Wg, const float* __restrict__ bg,
    u16* __restrict__ xb, u16* __restrict__ wqkvt, u16* __restrict__ wot,
    __half* __restrict__ logg) {
  __shared__ float smem[33 * 32];
  const int tid = threadIdx.x;
  const int gbid = blockIdx.x;

  if (gbid < 4096) {            // ---- cast x (4 floats/thread)
    const int i = gbid * 256 + tid;
    const float4 v = ((const float4*)x)[i];
    union { u16 u[4]; unsigned long long ll; } p;
    p.u[0] = f2b(v.x); p.u[1] = f2b(v.y); p.u[2] = f2b(v.z); p.u[3] = f2b(v.w);
    ((unsigned long long*)xb)[i] = p.ll;
    return;
  }
  if (gbid < 8192) {            // ---- W transpose+cast
    const int bid = gbid - 4096;
    const int which = bid >> 10;
    const int tr = (bid >> 5) & 31;
    const int tc = bid & 31;
    const float* W = which == 0 ? Wq : which == 1 ? Wk : which == 2 ? Wv : Wo;
    u16* dst = (which == 3) ? wot : (wqkvt + (long long)which * 1024 * 1024);
    const int tx = tid & 31, ty = tid >> 5;
    float* t = smem;
#pragma unroll
    for (int rr = 0; rr < 4; rr++)
      t[(ty + rr * 8) * 33 + tx] = W[(tr * 32 + ty + rr * 8) * 1024 + tc * 32 + tx];
    __syncthreads();
#pragma unroll
    for (int rr = 0; rr < 4; rr++)
      dst[(tc * 32 + ty + rr * 8) * 1024 + tr * 32 + tx] = f2b(t[tx * 33 + ty + rr * 8]);
    return;
  }
  // ---- geo prior: log(clip(relu(emb.Wg+bg),1e-6)) as fp16, (B,H,N,N)
  float* wg_s = smem;            // 512 floats
  float* bg_s = smem + 512;      // 8 floats
  wg_s[tid] = Wg[tid];
  wg_s[tid + 256] = Wg[tid + 256];
  if (tid < 8) bg_s[tid] = bg[tid];
  __syncthreads();
  const int bid = gbid - 8192;
  const int b = bid >> 8, i = bid & 255;
  const int j = tid;
  const float4 bi4 = ((const float4*)boxes)[b * 256 + i];
  const float4 bj4 = ((const float4*)boxes)[b * 256 + j];
  const float cxi = (bi4.x + bi4.z) * 0.5f, cyi = (bi4.y + bi4.w) * 0.5f;
  const float wi = bi4.z - bi4.x + 1.f, hi = bi4.w - bi4.y + 1.f;
  const float cxj = (bj4.x + bj4.z) * 0.5f, cyj = (bj4.y + bj4.w) * 0.5f;
  const float wj = bj4.z - bj4.x + 1.f, hj = bj4.w - bj4.y + 1.f;
  float pos[4];
  pos[0] = __logf(fmaxf(fabsf((cxi - cxj) / wi), 1e-3f));
  pos[1] = __logf(fmaxf(fabsf((cyi - cyj) / hi), 1e-3f));
  pos[2] = __logf(wi / wj);
  pos[3] = __logf(hi / hj);
  const float dimm[8] = {1.0f, 0.42169650342f, 0.177827941f, 0.0749894209f,
                         0.0316227766f, 0.01333521432f, 0.00562341325f, 0.00237137371f};
  float sv[32], cv[32];
#pragma unroll
  for (int d = 0; d < 4; d++)
#pragma unroll
    for (int f = 0; f < 8; f++) {
      const float ang = 100.f * pos[d] * dimm[f];
      __sincosf(ang, &sv[d * 8 + f], &cv[d * 8 + f]);
    }
  const long long base = ((long long)(b * 8) * 256 + i) * 256 + j;
#pragma unroll
  for (int h = 0; h < 8; h++) {
    float a = bg_s[h];
#pragma unroll
    for (int t = 0; t < 32; t++)
      a = fmaf(sv[t], wg_s[h * 64 + t], fmaf(cv[t], wg_s[h * 64 + 32 + t], a));
    logg[base + (long long)h * 65536] = __float2half(__logf(fmaxf(a, 1e-6f)));
  }
}

// ------------------------------------------------ qkv GEMM: 256x256 8-phase v2
// 2 barriers/phase, vmcnt folded into closing barrier. v written as vT directly.
#define LDA_SUB(AV, ihalf)                                                      \
  _Pragma("unroll") for (int i_ = 0; i_ < 4; i_++) {                            \
    const int row_ = wm * 128 + (ihalf) * 64 + i_ * 16 + fr;                    \
    AV[i_][0] = *(const bfrag*)(Asc + row_ * 64 + acol0);                       \
    AV[i_][1] = *(const bfrag*)(Asc + row_ * 64 + acol1);                       \
  }
#define LDB_SUB(BV, jhalf)                                                      \
  _Pragma("unroll") for (int j_ = 0; j_ < 2; j_++) {                            \
    const int row_ = wn * 64 + (jhalf) * 32 + j_ * 16 + fr;                     \
    BV[j_][0] = *(const bfrag*)(Bsc + row_ * 64 + acol0);                       \
    BV[j_][1] = *(const bfrag*)(Bsc + row_ * 64 + acol1);                       \
  }
#define QUAD(I0, J0, AV, BV)                                                    \
  _Pragma("unroll") for (int i_ = 0; i_ < 4; i_++)                              \
  _Pragma("unroll") for (int j_ = 0; j_ < 2; j_++)                              \
  _Pragma("unroll") for (int ks_ = 0; ks_ < 2; ks_++)                           \
    acc[(I0) + i_][(J0) + j_] =                                                 \
        MFMA16(AV[i_][ks_], BV[j_][ks_], acc[(I0) + i_][(J0) + j_]);
#define STG_A(kt_, r_, dA) \
  gload16(Agp + (long long)(r_) * 65536 + (kt_) * 64, (dA) + (r_) * 4096 + (w << 9))
#define STG_B(kt_, r_, dB) \
  gload16(Bgp + (long long)(r_) * 65536 + (kt_) * 64, (dB) + (r_) * 4096 + (w << 9))
#define BAR() __builtin_amdgcn_s_barrier()
#define PRIO1() __builtin_amdgcn_s_setprio(1)
#define PRIO0() __builtin_amdgcn_s_setprio(0)

__global__ __launch_bounds__(512, 1) void gemm256_qkv(
    const u16* __restrict__ A, const u16* __restrict__ Bt,
    const float* __restrict__ b0, const float* __restrict__ b1,
    const float* __restrict__ b2, u16* __restrict__ oq, u16* __restrict__ ok,
    u16* __restrict__ ovT) {
  __shared__ u16 AsF[2 * 16384];
  __shared__ u16 BsF[2 * 16384];
  const int tid = threadIdx.x, lane = tid & 63, w = tid >> 6;
  const int wm = w >> 2, wn = w & 3;
  const int fr = lane & 15, fq = lane >> 4;

  const int bid = (blockIdx.x & 7) * 24 + (blockIdx.x >> 3);  // XCD swizzle
  const int bm = bid / 12, bn = bid - bm * 12;
  const int m0 = bm << 8, n0 = bn << 8;

  const int acol0 = (fq * 8) ^ ((fr & 7) * 8);
  const int acol1 = (32 + fq * 8) ^ ((fr & 7) * 8);

  const int srw = tid >> 3;
  const int scol = (((tid & 7) ^ (srw & 7)) << 3);
  const u16* Agp = A + (long long)(m0 + srw) * 1024 + scol;
  const u16* Bgp = Bt + (long long)(n0 + srw) * 1024 + scol;

  f4 acc[8][4];
#pragma unroll
  for (int i = 0; i < 8; i++)
#pragma unroll
    for (int j = 0; j < 4; j++) acc[i][j] = (f4){0.f, 0.f, 0.f, 0.f};

  {  // prologue: stage tile 0, order [A0,A2,B0,B1,B2,B3,A1,A3]
    u16* dA = AsF; u16* dB = BsF;
    STG_A(0, 0, dA); STG_A(0, 2, dA);
    STG_B(0, 0, dB); STG_B(0, 1, dB); STG_B(0, 2, dB); STG_B(0, 3, dB);
    STG_A(0, 1, dA); STG_A(0, 3, dA);
  }
  asm volatile("s_waitcnt vmcnt(2)" ::: "memory");
  BAR();

  bfrag aV[4][2], b0V[2][2], b1V[2][2];

  for (int kt = 0; kt < 15; ++kt) {
    const int cur = kt & 1;
    const u16* Asc = AsF + cur * 16384;
    const u16* Bsc = BsF + cur * 16384;
    u16* dA = AsF + (cur ^ 1) * 16384;
    u16* dB = BsF + (cur ^ 1) * 16384;
    // p0
    LDA_SUB(aV, 0); LDB_SUB(b0V, 0);
    STG_A(kt + 1, 0, dA); STG_A(kt + 1, 2, dA);
    BAR();
    PRIO1(); QUAD(0, 0, aV, b0V); PRIO0();
    BAR();
    // p1
    LDB_SUB(b1V, 1);
    STG_B(kt + 1, 0, dB); STG_B(kt + 1, 1, dB);
    BAR();
    PRIO1(); QUAD(0, 2, aV, b1V); PRIO0();
    asm volatile("s_waitcnt vmcnt(4)" ::: "memory");  // old A1,A3 retired
    BAR();
    // p2
    LDA_SUB(aV, 1);
    STG_B(kt + 1, 2, dB); STG_B(kt + 1, 3, dB);
    BAR();
    PRIO1(); QUAD(4, 2, aV, b1V); PRIO0();
    BAR();
    // p3
    STG_A(kt + 1, 1, dA); STG_A(kt + 1, 3, dA);
    BAR();
    PRIO1(); QUAD(4, 0, aV, b0V); PRIO0();
    asm volatile("s_waitcnt vmcnt(2)" ::: "memory");  // next tile's first 6 halves
    BAR();
  }
  {  // peeled last K-tile (buf 1), no staging
    const u16* Asc = AsF + 16384;
    const u16* Bsc = BsF + 16384;
    LDA_SUB(aV, 0); LDB_SUB(b0V, 0);
    PRIO1(); QUAD(0, 0, aV, b0V); PRIO0();
    LDB_SUB(b1V, 1);
    PRIO1(); QUAD(0, 2, aV, b1V); PRIO0();
    asm volatile("s_waitcnt vmcnt(0)" ::: "memory");
    BAR();
    LDA_SUB(aV, 1);
    QUAD(4, 2, aV, b1V);
    QUAD(4, 0, aV, b0V);
  }

  // epilogue: bias; scale q; q,k -> (B,H,N,DK); v -> (B,H,DK,N) directly
#pragma unroll
  for (int j = 0; j < 4; j++) {
    const int n = n0 + wn * 64 + j * 16 + fr;
    const int which = n >> 10;
    const int hh = (n >> 7) & 7;
    const int dk = n & 127;
    const float bia = (which == 0 ? b0 : which == 1 ? b1 : b2)[n & 1023];
    const float scl = (which == 0) ? 0.08838834764831845f : 1.0f;  // 1/sqrt(DK)
#pragma unroll
    for (int i = 0; i < 8; i++)
#pragma unroll
      for (int r = 0; r < 4; r++) {
        const int m = m0 + wm * 128 + i * 16 + fq * 4 + r;
        const int bidx = m >> 8, itok = m & 255;
        const u16 val = f2b((acc[i][j][r] + bia) * scl);
        if (which == 2)
          ovT[((long long)(bidx * 8 + hh) * 128 + dk) * 256 + itok] = val;
        else
          (which == 0 ? oq : ok)[((long long)(bidx * 8 + hh) * 256 + itok) * 128 + dk] = val;
      }
  }
}

// ------------------------------------------------ out-proj GEMM: 128x64 tiles
__global__ __launch_bounds__(256) void gemm_out64(
    const u16* __restrict__ A, const u16* __restrict__ Bt,
    const float* __restrict__ b0, float* __restrict__ co) {
  __shared__ u16 As[128 * 32];
  __shared__ u16 Bs[64 * 32];
  const int bid = (blockIdx.x & 7) * 64 + (blockIdx.x >> 3);  // XCD swizzle (512)
  const int bm = bid >> 4, bn = bid & 15;
  const int m0 = bm << 7, n0 = bn << 6;
  const int tid = threadIdx.x, lane = tid & 63, w = tid >> 6;
  const int wr = w >> 1, wc = w & 1;
  const int fr = lane & 15, fq = lane >> 4;

  f4 acc[4][2];
#pragma unroll
  for (int i = 0; i < 4; i++)
#pragma unroll
    for (int j = 0; j < 2; j++) acc[i][j] = (f4){0.f, 0.f, 0.f, 0.f};

  const int sr = lane >> 2;
  const int skel = (lane & 3) << 3;
  const u16* Ag0 = A + (long long)(m0 + (w << 5) + sr) * 1024 + skel;
  const u16* Ag1 = Ag0 + 16 * 1024;
  const u16* Bg0 = Bt + (long long)(n0 + (w << 4) + sr) * 1024 + skel;
  u16* Al0 = As + (w << 5) * 32;
  u16* Al1 = Al0 + 16 * 32;
  u16* Bl0 = Bs + (w << 4) * 32;

  for (int k0 = 0; k0 < 1024; k0 += 32) {
    __syncthreads();
    gload16(Ag0 + k0, Al0);
    gload16(Ag1 + k0, Al1);
    gload16(Bg0 + k0, Bl0);
    __syncthreads();
    bfrag av[4], bv[2];
#pragma unroll
    for (int i = 0; i < 4; i++)
      av[i] = *(const bfrag*)(As + ((wr << 6) + (i << 4) + fr) * 32 + (fq << 3));
#pragma unroll
    for (int j = 0; j < 2; j++)
      bv[j] = *(const bfrag*)(Bs + ((wc << 5) + (j << 4) + fr) * 32 + (fq << 3));
#pragma unroll
    for (int i = 0; i < 4; i++)
#pragma unroll
      for (int j = 0; j < 2; j++) acc[i][j] = MFMA16(av[i], bv[j], acc[i][j]);
  }

#pragma unroll
  for (int i = 0; i < 4; i++)
#pragma unroll
    for (int j = 0; j < 2; j++) {
      const int n = n0 + (wc << 5) + (j << 4) + fr;
      const float bia = b0[n];
#pragma unroll
      for (int r = 0; r < 4; r++) {
        const int m = m0 + (wr << 6) + (i << 4) + (fq << 2) + r;
        co[(long long)m * 1024 + n] = acc[i][j][r] + bia;
      }
    }
}

// ---------------------------------------------------------------------- attention
// Flash split-K, 2 rg x 2 kh waves; K/V fragment double-buffer prefetch.
__global__ __launch_bounds__(256, 4) void attn_kernel(
    const u16* __restrict__ q, const u16* __restrict__ k,
    const u16* __restrict__ vT, const __half* __restrict__ logg,
    u16* __restrict__ aout) {
  __shared__ __align__(16) char smem[16384 + 17408 + 256];
  __half* ggs = (__half*)smem;
  u16* plds = (u16*)(smem + 16384);
  float* mbuf = (float*)(smem + 16384);
  float* mlb = (float*)(smem + 16384 + 17408);

  const int bid = ((blockIdx.x & 7) << 7) | (blockIdx.x >> 3);  // XCD swizzle
  const int qt = bid & 7;
  const int bh = bid >> 3;
  const int tid = threadIdx.x, lane = tid & 63, w = tid >> 6;
  const int rg = w >> 1, kh = w & 1;
  const int fr = lane & 15, fq = lane >> 4;
  const int i0 = qt * 32 + rg * 16;

  const u16* qp = q + (long long)bh * Nn * DKk;
  const u16* kp = k + (long long)bh * Nn * DKk + kh * 128 * DKk;
  const u16* vp = vT + (long long)bh * DKk * Nn;
  const __half* gp = logg + (long long)bh * Nn * Nn;

  __half* ggw = ggs + w * (16 * 128);
  {
    const int r4 = lane >> 4, c8 = lane & 15;
#pragma unroll
    for (int t = 0; t < 4; t++)
      gload16(gp + (i0 + t * 4 + r4) * Nn + kh * 128 + c8 * 8, ggw + t * 512);
  }

  bfrag qf[4];
#pragma unroll
  for (int ks = 0; ks < 4; ks++)
    qf[ks] = *(const bfrag*)(qp + (i0 + fr) * DKk + ks * 32 + fq * 8);

  f4 s[8];
#pragma unroll
  for (int j = 0; j < 8; j++) s[j] = (f4){0.f, 0.f, 0.f, 0.f};

  bfrag kfb[2][4];
#pragma unroll
  for (int ks = 0; ks < 4; ks++)
    kfb[0][ks] = *(const bfrag*)(kp + fr * DKk + ks * 32 + fq * 8);
#pragma unroll
  for (int j = 0; j < 8; j++) {
    if (j < 7) {
#pragma unroll
      for (int ks = 0; ks < 4; ks++)
        kfb[(j + 1) & 1][ks] =
            *(const bfrag*)(kp + ((j + 1) * 16 + fr) * DKk + ks * 32 + fq * 8);
    }
#pragma unroll
    for (int ks = 0; ks < 4; ks++) s[j] = MFMA16(qf[ks], kfb[j & 1][ks], s[j]);
  }

  asm volatile("s_waitcnt vmcnt(0)" ::: "memory");  // prior staged

#pragma unroll
  for (int j = 0; j < 8; j++)
#pragma unroll
    for (int r = 0; r < 4; r++)
      s[j][r] += __half2float(ggw[(fq * 4 + r) * 128 + j * 16 + fr]);

  float mr[4], lr[4];
#pragma unroll
  for (int r = 0; r < 4; r++) {
    float m = s[0][r];
#pragma unroll
    for (int j = 1; j < 8; j++) m = fmaxf(m, s[j][r]);
    m = fmaxf(m, __shfl_xor(m, 1));
    m = fmaxf(m, __shfl_xor(m, 2));
    m = fmaxf(m, __shfl_xor(m, 4));
    m = fmaxf(m, __shfl_xor(m, 8));
    float t = 0.f;
#pragma unroll
    for (int j = 0; j < 8; j++) {
      const float p = __expf(s[j][r] - m);
      s[j][r] = p;
      t += p;
    }
    t += __shfl_xor(t, 1);
    t += __shfl_xor(t, 2);
    t += __shfl_xor(t, 4);
    t += __shfl_xor(t, 8);
    mr[r] = m;
    lr[r] = t;
  }

  u16* pw = plds + w * (16 * 136);
#pragma unroll
  for (int j = 0; j < 8; j++)
#pragma unroll
    for (int r = 0; r < 4; r++)
      pw[(fq * 4 + r) * 136 + j * 16 + fr] = f2b(s[j][r]);
  __syncthreads();

  f4 o[8];
#pragma unroll
  for (int d = 0; d < 8; d++) o[d] = (f4){0.f, 0.f, 0.f, 0.f};
#pragma unroll
  for (int jt = 0; jt < 4; jt++) {
    bfrag pf = *(const bfrag*)(pw + fr * 136 + jt * 32 + fq * 8);
    bfrag vfb[2];
    vfb[0] = *(const bfrag*)(vp + fr * Nn + kh * 128 + jt * 32 + fq * 8);
#pragma unroll
    for (int d = 0; d < 8; d++) {
      if (d < 7)
        vfb[(d + 1) & 1] =
            *(const bfrag*)(vp + ((d + 1) * 16 + fr) * Nn + kh * 128 + jt * 32 + fq * 8);
      o[d] = MFMA16(pf, vfb[d & 1], o[d]);
    }
  }
  __syncthreads();

  if (kh) {
    float* ob = mbuf + rg * (16 * 132);
#pragma unroll
    for (int d = 0; d < 8; d++)
#pragma unroll
      for (int r = 0; r < 4; r++)
        ob[(fq * 4 + r) * 132 + d * 16 + fr] = o[d][r];
    if (fr == 0)
#pragma unroll
      for (int r = 0; r < 4; r++) {
        mlb[rg * 32 + (fq * 4 + r) * 2] = mr[r];
        mlb[rg * 32 + (fq * 4 + r) * 2 + 1] = lr[r];
      }
  }
  __syncthreads();

  if (!kh) {
    const int b = bh >> 3, h = bh & 7;
    float a0[4], a1[4], invl[4];
#pragma unroll
    for (int r = 0; r < 4; r++) {
      const float m1 = mlb[rg * 32 + (fq * 4 + r) * 2];
      const float l1 = mlb[rg * 32 + (fq * 4 + r) * 2 + 1];
      const float m = fmaxf(mr[r], m1);
      a0[r] = __expf(mr[r] - m);
      a1[r] = __expf(m1 - m);
      invl[r] = 1.0f / (lr[r] * a0[r] + l1 * a1[r]);
    }
    const float* ob = mbuf + rg * (16 * 132);
#pragma unroll
    for (int d = 0; d < 8; d++)
#pragma unroll
      for (int r = 0; r < 4; r++) {
        const float o1 = ob[(fq * 4 + r) * 132 + d * 16 + fr];
        const float val = (o[d][r] * a0[r] + o1 * a1[r]) * invl[r];
        const int row = i0 + fq * 4 + r;
        const int dk = d * 16 + fr;
        aout[((long long)(b * 256 + row)) * 1024 + h * 128 + dk] = f2b(val);
      }
  }
}

// ------------------------------------------------------------------------- launch
extern "C" void kernel_launch(void* const* d_in, const int* in_sizes, int n_in,
                              void* d_out, int out_size, void* d_ws, size_t ws_size,
                              hipStream_t stream) {
  (void)in_sizes; (void)n_in; (void)out_size; (void)ws_size;
  const float* x = (const float*)d_in[0];
  const float* boxes = (const float*)d_in[1];
  const float* Wq = (const float*)d_in[2];
  const float* bq = (const float*)d_in[3];
  const float* Wk = (const float*)d_in[4];
  const float* bk = (const float*)d_in[5];
  const float* Wv = (const float*)d_in[6];
  const float* bv = (const float*)d_in[7];
  const float* Wo = (const float*)d_in[8];
  const float* bo = (const float*)d_in[9];
  const float* Wg = (const float*)d_in[10];
  const float* bg = (const float*)d_in[11];
  float* out = (float*)d_out;

  char* ws = (char*)d_ws;
  u16* xb    = (u16*)(ws);                        // 8 MB  x as bf16 (4096x1024)
  u16* wqkvt = (u16*)(ws + (8ll << 20));          // 6 MB  [Wq|Wk|Wv]^T
  u16* wot   = (u16*)(ws + (14ll << 20));         // 2 MB  Wo^T
  u16* qb    = (u16*)(ws + (16ll << 20));         // 8 MB  (B,H,N,DK)
  u16* kb    = (u16*)(ws + (24ll << 20));         // 8 MB
  u16* vtb   = (u16*)(ws + (32ll << 20));         // 8 MB  (B,H,DK,N) direct
  __half* logg = (__half*)(ws + (48ll << 20));    // 16 MB (B,H,N,N) fp16
  u16* aout  = (u16*)(ws + (64ll << 20));         // 8 MB  (B,N,H*DK) bf16

  pre_kernel<<<12288, 256, 0, stream>>>(x, boxes, Wq, Wk, Wv, Wo, Wg, bg,
                                        xb, wqkvt, wot, logg);
  gemm256_qkv<<<192, 512, 0, stream>>>(xb, wqkvt, bq, bk, bv, qb, kb, vtb);
  attn_kernel<<<1024, 256, 0, stream>>>(qb, kb, vtb, logg, aout);
  gemm_out64<<<512, 256, 0, stream>>>(aout, wot, bo, out);
}

// Round 9
// 215.331 us; speedup vs baseline: 1.0837x; 1.0837x over previous
//
#include <hip/hip_runtime.h>
#include <hip/hip_fp16.h>

#define Nn 256
#define DKk 128

typedef unsigned short u16;
typedef __attribute__((ext_vector_type(8))) short bfrag;   // 8 bf16 = 4 VGPR
typedef __attribute__((ext_vector_type(4))) float f4;

#define MFMA16(a, b, c) __builtin_amdgcn_mfma_f32_16x16x32_bf16((a), (b), (c), 0, 0, 0)

__device__ __forceinline__ u16 f2b(float f) {
  unsigned int u = __builtin_bit_cast(unsigned int, f);
  u += 0x7fffu + ((u >> 16) & 1u);      // RNE
  return (u16)(u >> 16);
}

typedef __attribute__((address_space(1))) void GV;
typedef __attribute__((address_space(3))) void LV;
__device__ __forceinline__ void gload16(const void* g, void* l) {
  __builtin_amdgcn_global_load_lds((GV*)g, (LV*)l, 16, 0, 0);
}

// ------------------------------------- fused: cast x | transpose W | geo prior
// grid 12288: [0,4096) cast x->bf16; [4096,8192) W transpose+cast; [8192,12288) geo
__global__ __launch_bounds__(256) void pre_kernel(
    const float* __restrict__ x, const float* __restrict__ boxes,
    const float* __restrict__ Wq, const float* __restrict__ Wk,
    const float* __restrict__ Wv, const float* __restrict__ Wo,
    const float* __restrict__ Wg, const float* __restrict__ bg,
    u16* __restrict__ xb, u16* __restrict__ wqkvt, u16* __restrict__ wot,
    __half* __restrict__ logg) {
  __shared__ float smem[33 * 32];
  const int tid = threadIdx.x;
  const int gbid = blockIdx.x;

  if (gbid < 4096) {            // ---- cast x (4 floats/thread)
    const int i = gbid * 256 + tid;
    const float4 v = ((const float4*)x)[i];
    union { u16 u[4]; unsigned long long ll; } p;
    p.u[0] = f2b(v.x); p.u[1] = f2b(v.y); p.u[2] = f2b(v.z); p.u[3] = f2b(v.w);
    ((unsigned long long*)xb)[i] = p.ll;
    return;
  }
  if (gbid < 8192) {            // ---- W transpose+cast
    const int bid = gbid - 4096;
    const int which = bid >> 10;
    const int tr = (bid >> 5) & 31;
    const int tc = bid & 31;
    const float* W = which == 0 ? Wq : which == 1 ? Wk : which == 2 ? Wv : Wo;
    u16* dst = (which == 3) ? wot : (wqkvt + (long long)which * 1024 * 1024);
    const int tx = tid & 31, ty = tid >> 5;
    float* t = smem;
#pragma unroll
    for (int rr = 0; rr < 4; rr++)
      t[(ty + rr * 8) * 33 + tx] = W[(tr * 32 + ty + rr * 8) * 1024 + tc * 32 + tx];
    __syncthreads();
#pragma unroll
    for (int rr = 0; rr < 4; rr++)
      dst[(tc * 32 + ty + rr * 8) * 1024 + tr * 32 + tx] = f2b(t[tx * 33 + ty + rr * 8]);
    return;
  }
  // ---- geo prior: log(clip(relu(emb.Wg+bg),1e-6)) as fp16, (B,H,N,N)
  float* wg_s = smem;            // 512 floats
  float* bg_s = smem + 512;      // 8 floats
  wg_s[tid] = Wg[tid];
  wg_s[tid + 256] = Wg[tid + 256];
  if (tid < 8) bg_s[tid] = bg[tid];
  __syncthreads();
  const int bid = gbid - 8192;
  const int b = bid >> 8, i = bid & 255;
  const int j = tid;
  const float4 bi4 = ((const float4*)boxes)[b * 256 + i];
  const float4 bj4 = ((const float4*)boxes)[b * 256 + j];
  const float cxi = (bi4.x + bi4.z) * 0.5f, cyi = (bi4.y + bi4.w) * 0.5f;
  const float wi = bi4.z - bi4.x + 1.f, hi = bi4.w - bi4.y + 1.f;
  const float cxj = (bj4.x + bj4.z) * 0.5f, cyj = (bj4.y + bj4.w) * 0.5f;
  const float wj = bj4.z - bj4.x + 1.f, hj = bj4.w - bj4.y + 1.f;
  float pos[4];
  pos[0] = __logf(fmaxf(fabsf((cxi - cxj) / wi), 1e-3f));
  pos[1] = __logf(fmaxf(fabsf((cyi - cyj) / hi), 1e-3f));
  pos[2] = __logf(wi / wj);
  pos[3] = __logf(hi / hj);
  const float dimm[8] = {1.0f, 0.42169650342f, 0.177827941f, 0.0749894209f,
                         0.0316227766f, 0.01333521432f, 0.00562341325f, 0.00237137371f};
  float sv[32], cv[32];
#pragma unroll
  for (int d = 0; d < 4; d++)
#pragma unroll
    for (int f = 0; f < 8; f++) {
      const float ang = 100.f * pos[d] * dimm[f];
      __sincosf(ang, &sv[d * 8 + f], &cv[d * 8 + f]);
    }
  const long long base = ((long long)(b * 8) * 256 + i) * 256 + j;
#pragma unroll
  for (int h = 0; h < 8; h++) {
    float a = bg_s[h];
#pragma unroll
    for (int t = 0; t < 32; t++)
      a = fmaf(sv[t], wg_s[h * 64 + t], fmaf(cv[t], wg_s[h * 64 + 32 + t], a));
    logg[base + (long long)h * 65536] = __float2half(__logf(fmaxf(a, 1e-6f)));
  }
}

// ------------------------------------------- qkv GEMM: m97 128x128 2-phase
// A: 4096x1024. Bt: 3072x1024 (row = output col). Grid 768 x 256 threads.
// Epilogue: bias, q-scale, scatter q,k -> (B,H,N,DK); v -> (B,H,DK,N) direct.
__global__ __launch_bounds__(256) void gemm128_qkv(
    const u16* __restrict__ A, const u16* __restrict__ Bt,
    const float* __restrict__ b0, const float* __restrict__ b1,
    const float* __restrict__ b2, u16* __restrict__ oq, u16* __restrict__ ok,
    u16* __restrict__ ovT) {
  __shared__ u16 As[128 * 32];
  __shared__ u16 Bs[128 * 32];
  const int bm = blockIdx.x / 24, bn = blockIdx.x - bm * 24;
  const int m0 = bm << 7, n0 = bn << 7;
  const int tid = threadIdx.x, lane = tid & 63, w = tid >> 6;
  const int wr = w >> 1, wc = w & 1;
  const int fr = lane & 15, fq = lane >> 4;

  f4 acc[4][4];
#pragma unroll
  for (int i = 0; i < 4; i++)
#pragma unroll
    for (int j = 0; j < 4; j++) acc[i][j] = (f4){0.f, 0.f, 0.f, 0.f};

  // staging: wave w covers rows [w*32, w*32+32); lane l -> row l>>2, k (l&3)*8
  const int srow = (w << 5) + (lane >> 2);
  const int skel = (lane & 3) << 3;
  const u16* Ag0 = A + (long long)(m0 + srow) * 1024 + skel;
  const u16* Ag1 = Ag0 + 16 * 1024;
  const u16* Bg0 = Bt + (long long)(n0 + srow) * 1024 + skel;
  const u16* Bg1 = Bg0 + 16 * 1024;
  u16* Al0 = As + (w << 5) * 32;
  u16* Al1 = Al0 + 16 * 32;
  u16* Bl0 = Bs + (w << 5) * 32;
  u16* Bl1 = Bl0 + 16 * 32;

  for (int k0 = 0; k0 < 1024; k0 += 32) {
    __syncthreads();
    gload16(Ag0 + k0, Al0);
    gload16(Ag1 + k0, Al1);
    gload16(Bg0 + k0, Bl0);
    gload16(Bg1 + k0, Bl1);
    __syncthreads();
    bfrag av[4], bv[4];
#pragma unroll
    for (int i = 0; i < 4; i++)
      av[i] = *(const bfrag*)(As + ((wr << 6) + (i << 4) + fr) * 32 + (fq << 3));
#pragma unroll
    for (int j = 0; j < 4; j++)
      bv[j] = *(const bfrag*)(Bs + ((wc << 6) + (j << 4) + fr) * 32 + (fq << 3));
#pragma unroll
    for (int i = 0; i < 4; i++)
#pragma unroll
      for (int j = 0; j < 4; j++) acc[i][j] = MFMA16(av[i], bv[j], acc[i][j]);
  }

#pragma unroll
  for (int j = 0; j < 4; j++) {
    const int n = n0 + (wc << 6) + (j << 4) + fr;
    const int which = n >> 10;
    const int hh = (n >> 7) & 7;
    const int dk = n & 127;
    const float bia = (which == 0 ? b0 : which == 1 ? b1 : b2)[n & 1023];
    const float scl = (which == 0) ? 0.08838834764831845f : 1.0f;  // 1/sqrt(DK)
#pragma unroll
    for (int i = 0; i < 4; i++)
#pragma unroll
      for (int r = 0; r < 4; r++) {
        const int m = m0 + (wr << 6) + (i << 4) + (fq << 2) + r;
        const int bidx = m >> 8, itok = m & 255;
        const u16 val = f2b((acc[i][j][r] + bia) * scl);
        if (which == 2)
          ovT[((long long)(bidx * 8 + hh) * 128 + dk) * 256 + itok] = val;
        else
          (which == 0 ? oq : ok)[((long long)(bidx * 8 + hh) * 256 + itok) * 128 + dk] = val;
      }
  }
}

// ------------------------------------------------ out-proj GEMM: 128x64 tiles
__global__ __launch_bounds__(256) void gemm_out64(
    const u16* __restrict__ A, const u16* __restrict__ Bt,
    const float* __restrict__ b0, float* __restrict__ co) {
  __shared__ u16 As[128 * 32];
  __shared__ u16 Bs[64 * 32];
  const int bid = (blockIdx.x & 7) * 64 + (blockIdx.x >> 3);  // XCD swizzle (512)
  const int bm = bid >> 4, bn = bid & 15;
  const int m0 = bm << 7, n0 = bn << 6;
  const int tid = threadIdx.x, lane = tid & 63, w = tid >> 6;
  const int wr = w >> 1, wc = w & 1;
  const int fr = lane & 15, fq = lane >> 4;

  f4 acc[4][2];
#pragma unroll
  for (int i = 0; i < 4; i++)
#pragma unroll
    for (int j = 0; j < 2; j++) acc[i][j] = (f4){0.f, 0.f, 0.f, 0.f};

  const int sr = lane >> 2;
  const int skel = (lane & 3) << 3;
  const u16* Ag0 = A + (long long)(m0 + (w << 5) + sr) * 1024 + skel;
  const u16* Ag1 = Ag0 + 16 * 1024;
  const u16* Bg0 = Bt + (long long)(n0 + (w << 4) + sr) * 1024 + skel;
  u16* Al0 = As + (w << 5) * 32;
  u16* Al1 = Al0 + 16 * 32;
  u16* Bl0 = Bs + (w << 4) * 32;

  for (int k0 = 0; k0 < 1024; k0 += 32) {
    __syncthreads();
    gload16(Ag0 + k0, Al0);
    gload16(Ag1 + k0, Al1);
    gload16(Bg0 + k0, Bl0);
    __syncthreads();
    bfrag av[4], bv[2];
#pragma unroll
    for (int i = 0; i < 4; i++)
      av[i] = *(const bfrag*)(As + ((wr << 6) + (i << 4) + fr) * 32 + (fq << 3));
#pragma unroll
    for (int j = 0; j < 2; j++)
      bv[j] = *(const bfrag*)(Bs + ((wc << 5) + (j << 4) + fr) * 32 + (fq << 3));
#pragma unroll
    for (int i = 0; i < 4; i++)
#pragma unroll
      for (int j = 0; j < 2; j++) acc[i][j] = MFMA16(av[i], bv[j], acc[i][j]);
  }

#pragma unroll
  for (int i = 0; i < 4; i++)
#pragma unroll
    for (int j = 0; j < 2; j++) {
      const int n = n0 + (wc << 5) + (j << 4) + fr;
      const float bia = b0[n];
#pragma unroll
      for (int r = 0; r < 4; r++) {
        const int m = m0 + (wr << 6) + (i << 4) + (fq << 2) + r;
        co[(long long)m * 1024 + n] = acc[i][j][r] + bia;
      }
    }
}

// ---------------------------------------------------------------------- attention
// Flash split-K, 2 rg x 2 kh waves; K/V fragment double-buffer prefetch.
__global__ __launch_bounds__(256, 4) void attn_kernel(
    const u16* __restrict__ q, const u16* __restrict__ k,
    const u16* __restrict__ vT, const __half* __restrict__ logg,
    u16* __restrict__ aout) {
  __shared__ __align__(16) char smem[16384 + 17408 + 256];
  __half* ggs = (__half*)smem;
  u16* plds = (u16*)(smem + 16384);
  float* mbuf = (float*)(smem + 16384);
  float* mlb = (float*)(smem + 16384 + 17408);

  const int bid = ((blockIdx.x & 7) << 7) | (blockIdx.x >> 3);  // XCD swizzle
  const int qt = bid & 7;
  const int bh = bid >> 3;
  const int tid = threadIdx.x, lane = tid & 63, w = tid >> 6;
  const int rg = w >> 1, kh = w & 1;
  const int fr = lane & 15, fq = lane >> 4;
  const int i0 = qt * 32 + rg * 16;

  const u16* qp = q + (long long)bh * Nn * DKk;
  const u16* kp = k + (long long)bh * Nn * DKk + kh * 128 * DKk;
  const u16* vp = vT + (long long)bh * DKk * Nn;
  const __half* gp = logg + (long long)bh * Nn * Nn;

  __half* ggw = ggs + w * (16 * 128);
  {
    const int r4 = lane >> 4, c8 = lane & 15;
#pragma unroll
    for (int t = 0; t < 4; t++)
      gload16(gp + (i0 + t * 4 + r4) * Nn + kh * 128 + c8 * 8, ggw + t * 512);
  }

  bfrag qf[4];
#pragma unroll
  for (int ks = 0; ks < 4; ks++)
    qf[ks] = *(const bfrag*)(qp + (i0 + fr) * DKk + ks * 32 + fq * 8);

  f4 s[8];
#pragma unroll
  for (int j = 0; j < 8; j++) s[j] = (f4){0.f, 0.f, 0.f, 0.f};

  bfrag kfb[2][4];
#pragma unroll
  for (int ks = 0; ks < 4; ks++)
    kfb[0][ks] = *(const bfrag*)(kp + fr * DKk + ks * 32 + fq * 8);
#pragma unroll
  for (int j = 0; j < 8; j++) {
    if (j < 7) {
#pragma unroll
      for (int ks = 0; ks < 4; ks++)
        kfb[(j + 1) & 1][ks] =
            *(const bfrag*)(kp + ((j + 1) * 16 + fr) * DKk + ks * 32 + fq * 8);
    }
#pragma unroll
    for (int ks = 0; ks < 4; ks++) s[j] = MFMA16(qf[ks], kfb[j & 1][ks], s[j]);
  }

  asm volatile("s_waitcnt vmcnt(0)" ::: "memory");  // prior staged

#pragma unroll
  for (int j = 0; j < 8; j++)
#pragma unroll
    for (int r = 0; r < 4; r++)
      s[j][r] += __half2float(ggw[(fq * 4 + r) * 128 + j * 16 + fr]);

  float mr[4], lr[4];
#pragma unroll
  for (int r = 0; r < 4; r++) {
    float m = s[0][r];
#pragma unroll
    for (int j = 1; j < 8; j++) m = fmaxf(m, s[j][r]);
    m = fmaxf(m, __shfl_xor(m, 1));
    m = fmaxf(m, __shfl_xor(m, 2));
    m = fmaxf(m, __shfl_xor(m, 4));
    m = fmaxf(m, __shfl_xor(m, 8));
    float t = 0.f;
#pragma unroll
    for (int j = 0; j < 8; j++) {
      const float p = __expf(s[j][r] - m);
      s[j][r] = p;
      t += p;
    }
    t += __shfl_xor(t, 1);
    t += __shfl_xor(t, 2);
    t += __shfl_xor(t, 4);
    t += __shfl_xor(t, 8);
    mr[r] = m;
    lr[r] = t;
  }

  u16* pw = plds + w * (16 * 136);
#pragma unroll
  for (int j = 0; j < 8; j++)
#pragma unroll
    for (int r = 0; r < 4; r++)
      pw[(fq * 4 + r) * 136 + j * 16 + fr] = f2b(s[j][r]);
  __syncthreads();

  f4 o[8];
#pragma unroll
  for (int d = 0; d < 8; d++) o[d] = (f4){0.f, 0.f, 0.f, 0.f};
#pragma unroll
  for (int jt = 0; jt < 4; jt++) {
    bfrag pf = *(const bfrag*)(pw + fr * 136 + jt * 32 + fq * 8);
    bfrag vfb[2];
    vfb[0] = *(const bfrag*)(vp + fr * Nn + kh * 128 + jt * 32 + fq * 8);
#pragma unroll
    for (int d = 0; d < 8; d++) {
      if (d < 7)
        vfb[(d + 1) & 1] =
            *(const bfrag*)(vp + ((d + 1) * 16 + fr) * Nn + kh * 128 + jt * 32 + fq * 8);
      o[d] = MFMA16(pf, vfb[d & 1], o[d]);
    }
  }
  __syncthreads();

  if (kh) {
    float* ob = mbuf + rg * (16 * 132);
#pragma unroll
    for (int d = 0; d < 8; d++)
#pragma unroll
      for (int r = 0; r < 4; r++)
        ob[(fq * 4 + r) * 132 + d * 16 + fr] = o[d][r];
    if (fr == 0)
#pragma unroll
      for (int r = 0; r < 4; r++) {
        mlb[rg * 32 + (fq * 4 + r) * 2] = mr[r];
        mlb[rg * 32 + (fq * 4 + r) * 2 + 1] = lr[r];
      }
  }
  __syncthreads();

  if (!kh) {
    const int b = bh >> 3, h = bh & 7;
    float a0[4], a1[4], invl[4];
#pragma unroll
    for (int r = 0; r < 4; r++) {
      const float m1 = mlb[rg * 32 + (fq * 4 + r) * 2];
      const float l1 = mlb[rg * 32 + (fq * 4 + r) * 2 + 1];
      const float m = fmaxf(mr[r], m1);
      a0[r] = __expf(mr[r] - m);
      a1[r] = __expf(m1 - m);
      invl[r] = 1.0f / (lr[r] * a0[r] + l1 * a1[r]);
    }
    const float* ob = mbuf + rg * (16 * 132);
#pragma unroll
    for (int d = 0; d < 8; d++)
#pragma unroll
      for (int r = 0; r < 4; r++) {
        const float o1 = ob[(fq * 4 + r) * 132 + d * 16 + fr];
        const float val = (o[d][r] * a0[r] + o1 * a1[r]) * invl[r];
        const int row = i0 + fq * 4 + r;
        const int dk = d * 16 + fr;
        aout[((long long)(b * 256 + row)) * 1024 + h * 128 + dk] = f2b(val);
      }
  }
}

// ------------------------------------------------------------------------- launch
extern "C" void kernel_launch(void* const* d_in, const int* in_sizes, int n_in,
                              void* d_out, int out_size, void* d_ws, size_t ws_size,
                              hipStream_t stream) {
  (void)in_sizes; (void)n_in; (void)out_size; (void)ws_size;
  const float* x = (const float*)d_in[0];
  const float* boxes = (const float*)d_in[1];
  const float* Wq = (const float*)d_in[2];
  const float* bq = (const float*)d_in[3];
  const float* Wk = (const float*)d_in[4];
  const float* bk = (const float*)d_in[5];
  const float* Wv = (const float*)d_in[6];
  const float* bv = (const float*)d_in[7];
  const float* Wo = (const float*)d_in[8];
  const float* bo = (const float*)d_in[9];
  const float* Wg = (const float*)d_in[10];
  const float* bg = (const float*)d_in[11];
  float* out = (float*)d_out;

  char* ws = (char*)d_ws;
  u16* xb    = (u16*)(ws);                        // 8 MB  x as bf16 (4096x1024)
  u16* wqkvt = (u16*)(ws + (8ll << 20));          // 6 MB  [Wq|Wk|Wv]^T
  u16* wot   = (u16*)(ws + (14ll << 20));         // 2 MB  Wo^T
  u16* qb    = (u16*)(ws + (16ll << 20));         // 8 MB  (B,H,N,DK)
  u16* kb    = (u16*)(ws + (24ll << 20));         // 8 MB
  u16* vtb   = (u16*)(ws + (32ll << 20));         // 8 MB  (B,H,DK,N) direct
  __half* logg = (__half*)(ws + (48ll << 20));    // 16 MB (B,H,N,N) fp16
  u16* aout  = (u16*)(ws + (64ll << 20));         // 8 MB  (B,N,H*DK) bf16

  pre_kernel<<<12288, 256, 0, stream>>>(x, boxes, Wq, Wk, Wv, Wo, Wg, bg,
                                        xb, wqkvt, wot, logg);
  gemm128_qkv<<<768, 256, 0, stream>>>(xb, wqkvt, bq, bk, bv, qb, kb, vtb);
  attn_kernel<<<1024, 256, 0, stream>>>(qb, kb, vtb, logg, aout);
  gemm_out64<<<512, 256, 0, stream>>>(aout, wot, bo, out);
}

// Round 10
// 210.384 us; speedup vs baseline: 1.1092x; 1.0235x over previous
//
#include <hip/hip_runtime.h>
#include <hip/hip_fp16.h>

#define Nn 256
#define DKk 128

typedef unsigned short u16;
typedef __attribute__((ext_vector_type(8))) short bfrag;   // 8 bf16 = 4 VGPR
typedef __attribute__((ext_vector_type(4))) float f4;

#define MFMA16(a, b, c) __builtin_amdgcn_mfma_f32_16x16x32_bf16((a), (b), (c), 0, 0, 0)

__device__ __forceinline__ u16 f2b(float f) {
  unsigned int u = __builtin_bit_cast(unsigned int, f);
  u += 0x7fffu + ((u >> 16) & 1u);      // RNE
  return (u16)(u >> 16);
}

typedef __attribute__((address_space(1))) void GV;
typedef __attribute__((address_space(3))) void LV;
__device__ __forceinline__ void gload16(const void* g, void* l) {
  __builtin_amdgcn_global_load_lds((GV*)g, (LV*)l, 16, 0, 0);
}

// ------------------------------------- fused: cast x | transpose W | geo prior
// grid 12288: [0,4096) cast x->bf16; [4096,8192) W transpose+cast; [8192,12288) geo
__global__ __launch_bounds__(256) void pre_kernel(
    const float* __restrict__ x, const float* __restrict__ boxes,
    const float* __restrict__ Wq, const float* __restrict__ Wk,
    const float* __restrict__ Wv, const float* __restrict__ Wo,
    const float* __restrict__ Wg, const float* __restrict__ bg,
    u16* __restrict__ xb, u16* __restrict__ wqkvt, u16* __restrict__ wot,
    __half* __restrict__ logg) {
  __shared__ float smem[33 * 32];
  const int tid = threadIdx.x;
  const int gbid = blockIdx.x;

  if (gbid < 4096) {            // ---- cast x (4 floats/thread)
    const int i = gbid * 256 + tid;
    const float4 v = ((const float4*)x)[i];
    union { u16 u[4]; unsigned long long ll; } p;
    p.u[0] = f2b(v.x); p.u[1] = f2b(v.y); p.u[2] = f2b(v.z); p.u[3] = f2b(v.w);
    ((unsigned long long*)xb)[i] = p.ll;
    return;
  }
  if (gbid < 8192) {            // ---- W transpose+cast
    const int bid = gbid - 4096;
    const int which = bid >> 10;
    const int tr = (bid >> 5) & 31;
    const int tc = bid & 31;
    const float* W = which == 0 ? Wq : which == 1 ? Wk : which == 2 ? Wv : Wo;
    u16* dst = (which == 3) ? wot : (wqkvt + (long long)which * 1024 * 1024);
    const int tx = tid & 31, ty = tid >> 5;
    float* t = smem;
#pragma unroll
    for (int rr = 0; rr < 4; rr++)
      t[(ty + rr * 8) * 33 + tx] = W[(tr * 32 + ty + rr * 8) * 1024 + tc * 32 + tx];
    __syncthreads();
#pragma unroll
    for (int rr = 0; rr < 4; rr++)
      dst[(tc * 32 + ty + rr * 8) * 1024 + tr * 32 + tx] = f2b(t[tx * 33 + ty + rr * 8]);
    return;
  }
  // ---- geo prior: log(clip(relu(emb.Wg+bg),1e-6)) as fp16, (B,H,N,N)
  // All transcendentals on the HW trans pipe (no ocml): log2-domain deltas
  // (kills the divisions + fuses the clip), v_sin/v_cos in revolutions.
  float* wg_s = smem;            // 512 floats
  float* bg_s = smem + 512;      // 8 floats
  wg_s[tid] = Wg[tid];
  wg_s[tid + 256] = Wg[tid + 256];
  if (tid < 8) bg_s[tid] = bg[tid];
  __syncthreads();
  const int bid = gbid - 8192;
  const int b = bid >> 8, i = bid & 255;
  const int j = tid;
  const float4 bi4 = ((const float4*)boxes)[b * 256 + i];
  const float4 bj4 = ((const float4*)boxes)[b * 256 + j];
  const float cxi = (bi4.x + bi4.z) * 0.5f, cyi = (bi4.y + bi4.w) * 0.5f;
  const float wi = bi4.z - bi4.x + 1.f, hi = bi4.w - bi4.y + 1.f;
  const float cxj = (bj4.x + bj4.z) * 0.5f, cyj = (bj4.y + bj4.w) * 0.5f;
  const float wj = bj4.z - bj4.x + 1.f, hj = bj4.w - bj4.y + 1.f;
  const float L2EPS = -9.965784284662087f;           // log2(1e-3)
  // pos deltas in log2 units: posl2[d] = log(...)/ln2
  float posl2[4];
  {
    const float ldx = __builtin_amdgcn_logf(fabsf(cxi - cxj));  // log2; -inf ok
    const float ldy = __builtin_amdgcn_logf(fabsf(cyi - cyj));
    const float lwi = __builtin_amdgcn_logf(wi);
    const float lhi = __builtin_amdgcn_logf(hi);
    const float lwj = __builtin_amdgcn_logf(wj);
    const float lhj = __builtin_amdgcn_logf(hj);
    posl2[0] = fmaxf(ldx - lwi, L2EPS);
    posl2[1] = fmaxf(ldy - lhi, L2EPS);
    posl2[2] = lwi - lwj;
    posl2[3] = lhi - lhj;
  }
  // angle (radians) = 100 * ln2 * posl2 * dimm[f]; revolutions = angle/(2pi)
  // revc[f] = 100*ln2/(2pi) * dimm[f] = 11.0317807 * dimm[f]
  const float revc[8] = {11.0317807f, 4.6520580f, 1.9617240f, 0.8272670f,
                         0.3488544f,  0.1471094f, 0.0620381f, 0.0261601f};
  float sv[32], cv[32];
#pragma unroll
  for (int d = 0; d < 4; d++)
#pragma unroll
    for (int f = 0; f < 8; f++) {
      float rev = posl2[d] * revc[f];
      rev = rev - floorf(rev);                      // [0,1): valid v_sin input
      sv[d * 8 + f] = __builtin_amdgcn_sinf(rev);   // sin(2pi*rev)
      cv[d * 8 + f] = __builtin_amdgcn_cosf(rev);
    }
  const long long base = ((long long)(b * 8) * 256 + i) * 256 + j;
  const float L2EPS6 = -19.931568569324174f;        // log2(1e-6)
#pragma unroll
  for (int h = 0; h < 8; h++) {
    float a = bg_s[h];
#pragma unroll
    for (int t = 0; t < 32; t++)
      a = fmaf(sv[t], wg_s[h * 64 + t], fmaf(cv[t], wg_s[h * 64 + 32 + t], a));
    // ln(clip(relu(a),1e-6)) = ln2 * max(log2(a), log2(1e-6));  log2(neg)=NaN,
    // log2(0)=-inf -> v_max picks the clamp either way.
    const float lg = fmaxf(__builtin_amdgcn_logf(a), L2EPS6) * 0.6931471805599453f;
    logg[base + (long long)h * 65536] = __float2half(lg);
  }
}

// ------------------------------------------- qkv GEMM: m97 128x128 2-phase
// A: 4096x1024. Bt: 3072x1024 (row = output col). Grid 768 x 256 threads.
// Epilogue: bias, q-scale, scatter q,k -> (B,H,N,DK); v -> (B,H,DK,N) direct.
__global__ __launch_bounds__(256) void gemm128_qkv(
    const u16* __restrict__ A, const u16* __restrict__ Bt,
    const float* __restrict__ b0, const float* __restrict__ b1,
    const float* __restrict__ b2, u16* __restrict__ oq, u16* __restrict__ ok,
    u16* __restrict__ ovT) {
  __shared__ u16 As[128 * 32];
  __shared__ u16 Bs[128 * 32];
  const int bm = blockIdx.x / 24, bn = blockIdx.x - bm * 24;
  const int m0 = bm << 7, n0 = bn << 7;
  const int tid = threadIdx.x, lane = tid & 63, w = tid >> 6;
  const int wr = w >> 1, wc = w & 1;
  const int fr = lane & 15, fq = lane >> 4;

  f4 acc[4][4];
#pragma unroll
  for (int i = 0; i < 4; i++)
#pragma unroll
    for (int j = 0; j < 4; j++) acc[i][j] = (f4){0.f, 0.f, 0.f, 0.f};

  // staging: wave w covers rows [w*32, w*32+32); lane l -> row l>>2, k (l&3)*8
  const int srow = (w << 5) + (lane >> 2);
  const int skel = (lane & 3) << 3;
  const u16* Ag0 = A + (long long)(m0 + srow) * 1024 + skel;
  const u16* Ag1 = Ag0 + 16 * 1024;
  const u16* Bg0 = Bt + (long long)(n0 + srow) * 1024 + skel;
  const u16* Bg1 = Bg0 + 16 * 1024;
  u16* Al0 = As + (w << 5) * 32;
  u16* Al1 = Al0 + 16 * 32;
  u16* Bl0 = Bs + (w << 5) * 32;
  u16* Bl1 = Bl0 + 16 * 32;

  for (int k0 = 0; k0 < 1024; k0 += 32) {
    __syncthreads();
    gload16(Ag0 + k0, Al0);
    gload16(Ag1 + k0, Al1);
    gload16(Bg0 + k0, Bl0);
    gload16(Bg1 + k0, Bl1);
    __syncthreads();
    bfrag av[4], bv[4];
#pragma unroll
    for (int i = 0; i < 4; i++)
      av[i] = *(const bfrag*)(As + ((wr << 6) + (i << 4) + fr) * 32 + (fq << 3));
#pragma unroll
    for (int j = 0; j < 4; j++)
      bv[j] = *(const bfrag*)(Bs + ((wc << 6) + (j << 4) + fr) * 32 + (fq << 3));
#pragma unroll
    for (int i = 0; i < 4; i++)
#pragma unroll
      for (int j = 0; j < 4; j++) acc[i][j] = MFMA16(av[i], bv[j], acc[i][j]);
  }

#pragma unroll
  for (int j = 0; j < 4; j++) {
    const int n = n0 + (wc << 6) + (j << 4) + fr;
    const int which = n >> 10;
    const int hh = (n >> 7) & 7;
    const int dk = n & 127;
    const float bia = (which == 0 ? b0 : which == 1 ? b1 : b2)[n & 1023];
    const float scl = (which == 0) ? 0.08838834764831845f : 1.0f;  // 1/sqrt(DK)
#pragma unroll
    for (int i = 0; i < 4; i++)
#pragma unroll
      for (int r = 0; r < 4; r++) {
        const int m = m0 + (wr << 6) + (i << 4) + (fq << 2) + r;
        const int bidx = m >> 8, itok = m & 255;
        const u16 val = f2b((acc[i][j][r] + bia) * scl);
        if (which == 2)
          ovT[((long long)(bidx * 8 + hh) * 128 + dk) * 256 + itok] = val;
        else
          (which == 0 ? oq : ok)[((long long)(bidx * 8 + hh) * 256 + itok) * 128 + dk] = val;
      }
  }
}

// ------------------------------------------------ out-proj GEMM: 128x64 tiles
__global__ __launch_bounds__(256) void gemm_out64(
    const u16* __restrict__ A, const u16* __restrict__ Bt,
    const float* __restrict__ b0, float* __restrict__ co) {
  __shared__ u16 As[128 * 32];
  __shared__ u16 Bs[64 * 32];
  const int bid = (blockIdx.x & 7) * 64 + (blockIdx.x >> 3);  // XCD swizzle (512)
  const int bm = bid >> 4, bn = bid & 15;
  const int m0 = bm << 7, n0 = bn << 6;
  const int tid = threadIdx.x, lane = tid & 63, w = tid >> 6;
  const int wr = w >> 1, wc = w & 1;
  const int fr = lane & 15, fq = lane >> 4;

  f4 acc[4][2];
#pragma unroll
  for (int i = 0; i < 4; i++)
#pragma unroll
    for (int j = 0; j < 2; j++) acc[i][j] = (f4){0.f, 0.f, 0.f, 0.f};

  const int sr = lane >> 2;
  const int skel = (lane & 3) << 3;
  const u16* Ag0 = A + (long long)(m0 + (w << 5) + sr) * 1024 + skel;
  const u16* Ag1 = Ag0 + 16 * 1024;
  const u16* Bg0 = Bt + (long long)(n0 + (w << 4) + sr) * 1024 + skel;
  u16* Al0 = As + (w << 5) * 32;
  u16* Al1 = Al0 + 16 * 32;
  u16* Bl0 = Bs + (w << 4) * 32;

  for (int k0 = 0; k0 < 1024; k0 += 32) {
    __syncthreads();
    gload16(Ag0 + k0, Al0);
    gload16(Ag1 + k0, Al1);
    gload16(Bg0 + k0, Bl0);
    __syncthreads();
    bfrag av[4], bv[2];
#pragma unroll
    for (int i = 0; i < 4; i++)
      av[i] = *(const bfrag*)(As + ((wr << 6) + (i << 4) + fr) * 32 + (fq << 3));
#pragma unroll
    for (int j = 0; j < 2; j++)
      bv[j] = *(const bfrag*)(Bs + ((wc << 5) + (j << 4) + fr) * 32 + (fq << 3));
#pragma unroll
    for (int i = 0; i < 4; i++)
#pragma unroll
      for (int j = 0; j < 2; j++) acc[i][j] = MFMA16(av[i], bv[j], acc[i][j]);
  }

#pragma unroll
  for (int i = 0; i < 4; i++)
#pragma unroll
    for (int j = 0; j < 2; j++) {
      const int n = n0 + (wc << 5) + (j << 4) + fr;
      const float bia = b0[n];
#pragma unroll
      for (int r = 0; r < 4; r++) {
        const int m = m0 + (wr << 6) + (i << 4) + (fq << 2) + r;
        co[(long long)m * 1024 + n] = acc[i][j][r] + bia;
      }
    }
}

// ---------------------------------------------------------------------- attention
// Flash split-K, 2 rg x 2 kh waves; K/V fragment double-buffer prefetch.
__global__ __launch_bounds__(256, 4) void attn_kernel(
    const u16* __restrict__ q, const u16* __restrict__ k,
    const u16* __restrict__ vT, const __half* __restrict__ logg,
    u16* __restrict__ aout) {
  __shared__ __align__(16) char smem[16384 + 17408 + 256];
  __half* ggs = (__half*)smem;
  u16* plds = (u16*)(smem + 16384);
  float* mbuf = (float*)(smem + 16384);
  float* mlb = (float*)(smem + 16384 + 17408);

  const int bid = ((blockIdx.x & 7) << 7) | (blockIdx.x >> 3);  // XCD swizzle
  const int qt = bid & 7;
  const int bh = bid >> 3;
  const int tid = threadIdx.x, lane = tid & 63, w = tid >> 6;
  const int rg = w >> 1, kh = w & 1;
  const int fr = lane & 15, fq = lane >> 4;
  const int i0 = qt * 32 + rg * 16;

  const u16* qp = q + (long long)bh * Nn * DKk;
  const u16* kp = k + (long long)bh * Nn * DKk + kh * 128 * DKk;
  const u16* vp = vT + (long long)bh * DKk * Nn;
  const __half* gp = logg + (long long)bh * Nn * Nn;

  __half* ggw = ggs + w * (16 * 128);
  {
    const int r4 = lane >> 4, c8 = lane & 15;
#pragma unroll
    for (int t = 0; t < 4; t++)
      gload16(gp + (i0 + t * 4 + r4) * Nn + kh * 128 + c8 * 8, ggw + t * 512);
  }

  bfrag qf[4];
#pragma unroll
  for (int ks = 0; ks < 4; ks++)
    qf[ks] = *(const bfrag*)(qp + (i0 + fr) * DKk + ks * 32 + fq * 8);

  f4 s[8];
#pragma unroll
  for (int j = 0; j < 8; j++) s[j] = (f4){0.f, 0.f, 0.f, 0.f};

  bfrag kfb[2][4];
#pragma unroll
  for (int ks = 0; ks < 4; ks++)
    kfb[0][ks] = *(const bfrag*)(kp + fr * DKk + ks * 32 + fq * 8);
#pragma unroll
  for (int j = 0; j < 8; j++) {
    if (j < 7) {
#pragma unroll
      for (int ks = 0; ks < 4; ks++)
        kfb[(j + 1) & 1][ks] =
            *(const bfrag*)(kp + ((j + 1) * 16 + fr) * DKk + ks * 32 + fq * 8);
    }
#pragma unroll
    for (int ks = 0; ks < 4; ks++) s[j] = MFMA16(qf[ks], kfb[j & 1][ks], s[j]);
  }

  asm volatile("s_waitcnt vmcnt(0)" ::: "memory");  // prior staged

#pragma unroll
  for (int j = 0; j < 8; j++)
#pragma unroll
    for (int r = 0; r < 4; r++)
      s[j][r] += __half2float(ggw[(fq * 4 + r) * 128 + j * 16 + fr]);

  float mr[4], lr[4];
#pragma unroll
  for (int r = 0; r < 4; r++) {
    float m = s[0][r];
#pragma unroll
    for (int j = 1; j < 8; j++) m = fmaxf(m, s[j][r]);
    m = fmaxf(m, __shfl_xor(m, 1));
    m = fmaxf(m, __shfl_xor(m, 2));
    m = fmaxf(m, __shfl_xor(m, 4));
    m = fmaxf(m, __shfl_xor(m, 8));
    float t = 0.f;
#pragma unroll
    for (int j = 0; j < 8; j++) {
      const float p = __expf(s[j][r] - m);
      s[j][r] = p;
      t += p;
    }
    t += __shfl_xor(t, 1);
    t += __shfl_xor(t, 2);
    t += __shfl_xor(t, 4);
    t += __shfl_xor(t, 8);
    mr[r] = m;
    lr[r] = t;
  }

  u16* pw = plds + w * (16 * 136);
#pragma unroll
  for (int j = 0; j < 8; j++)
#pragma unroll
    for (int r = 0; r < 4; r++)
      pw[(fq * 4 + r) * 136 + j * 16 + fr] = f2b(s[j][r]);
  __syncthreads();

  f4 o[8];
#pragma unroll
  for (int d = 0; d < 8; d++) o[d] = (f4){0.f, 0.f, 0.f, 0.f};
#pragma unroll
  for (int jt = 0; jt < 4; jt++) {
    bfrag pf = *(const bfrag*)(pw + fr * 136 + jt * 32 + fq * 8);
    bfrag vfb[2];
    vfb[0] = *(const bfrag*)(vp + fr * Nn + kh * 128 + jt * 32 + fq * 8);
#pragma unroll
    for (int d = 0; d < 8; d++) {
      if (d < 7)
        vfb[(d + 1) & 1] =
            *(const bfrag*)(vp + ((d + 1) * 16 + fr) * Nn + kh * 128 + jt * 32 + fq * 8);
      o[d] = MFMA16(pf, vfb[d & 1], o[d]);
    }
  }
  __syncthreads();

  if (kh) {
    float* ob = mbuf + rg * (16 * 132);
#pragma unroll
    for (int d = 0; d < 8; d++)
#pragma unroll
      for (int r = 0; r < 4; r++)
        ob[(fq * 4 + r) * 132 + d * 16 + fr] = o[d][r];
    if (fr == 0)
#pragma unroll
      for (int r = 0; r < 4; r++) {
        mlb[rg * 32 + (fq * 4 + r) * 2] = mr[r];
        mlb[rg * 32 + (fq * 4 + r) * 2 + 1] = lr[r];
      }
  }
  __syncthreads();

  if (!kh) {
    const int b = bh >> 3, h = bh & 7;
    float a0[4], a1[4], invl[4];
#pragma unroll
    for (int r = 0; r < 4; r++) {
      const float m1 = mlb[rg * 32 + (fq * 4 + r) * 2];
      const float l1 = mlb[rg * 32 + (fq * 4 + r) * 2 + 1];
      const float m = fmaxf(mr[r], m1);
      a0[r] = __expf(mr[r] - m);
      a1[r] = __expf(m1 - m);
      invl[r] = 1.0f / (lr[r] * a0[r] + l1 * a1[r]);
    }
    const float* ob = mbuf + rg * (16 * 132);
#pragma unroll
    for (int d = 0; d < 8; d++)
#pragma unroll
      for (int r = 0; r < 4; r++) {
        const float o1 = ob[(fq * 4 + r) * 132 + d * 16 + fr];
        const float val = (o[d][r] * a0[r] + o1 * a1[r]) * invl[r];
        const int row = i0 + fq * 4 + r;
        const int dk = d * 16 + fr;
        aout[((long long)(b * 256 + row)) * 1024 + h * 128 + dk] = f2b(val);
      }
  }
}

// ------------------------------------------------------------------------- launch
extern "C" void kernel_launch(void* const* d_in, const int* in_sizes, int n_in,
                              void* d_out, int out_size, void* d_ws, size_t ws_size,
                              hipStream_t stream) {
  (void)in_sizes; (void)n_in; (void)out_size; (void)ws_size;
  const float* x = (const float*)d_in[0];
  const float* boxes = (const float*)d_in[1];
  const float* Wq = (const float*)d_in[2];
  const float* bq = (const float*)d_in[3];
  const float* Wk = (const float*)d_in[4];
  const float* bk = (const float*)d_in[5];
  const float* Wv = (const float*)d_in[6];
  const float* bv = (const float*)d_in[7];
  const float* Wo = (const float*)d_in[8];
  const float* bo = (const float*)d_in[9];
  const float* Wg = (const float*)d_in[10];
  const float* bg = (const float*)d_in[11];
  float* out = (float*)d_out;

  char* ws = (char*)d_ws;
  u16* xb    = (u16*)(ws);                        // 8 MB  x as bf16 (4096x1024)
  u16* wqkvt = (u16*)(ws + (8ll << 20));          // 6 MB  [Wq|Wk|Wv]^T
  u16* wot   = (u16*)(ws + (14ll << 20));         // 2 MB  Wo^T
  u16* qb    = (u16*)(ws + (16ll << 20));         // 8 MB  (B,H,N,DK)
  u16* kb    = (u16*)(ws + (24ll << 20));         // 8 MB
  u16* vtb   = (u16*)(ws + (32ll << 20));         // 8 MB  (B,H,DK,N) direct
  __half* logg = (__half*)(ws + (48ll << 20));    // 16 MB (B,H,N,N) fp16
  u16* aout  = (u16*)(ws + (64ll << 20));         // 8 MB  (B,N,H*DK) bf16

  pre_kernel<<<12288, 256, 0, stream>>>(x, boxes, Wq, Wk, Wv, Wo, Wg, bg,
                                        xb, wqkvt, wot, logg);
  gemm128_qkv<<<768, 256, 0, stream>>>(xb, wqkvt, bq, bk, bv, qb, kb, vtb);
  attn_kernel<<<1024, 256, 0, stream>>>(qb, kb, vtb, logg, aout);
  gemm_out64<<<512, 256, 0, stream>>>(aout, wot, bo, out);
}